// Round 1
// baseline (485.073 us; speedup 1.0000x reference)
//
#include <hip/hip_runtime.h>

// Grouped vector quantizer, fp32-exact baseline.
// x: [8,2048,512] f32, codebook: [8,1024,64] f32, out: [8,2048,512] f32.
// out[t, g*64:(g+1)*64] = codebook[g, argmin_k ||x_seg - c_k||^2]
// (STE forward value == quantized vector).
//
// Design: 1 thread per (token, group). Block = 512 threads = 8 waves;
// wave w <-> group w (wave-uniform via readfirstlane so codebook row
// reads become scalar s_loads overlapping the VALU FMA stream).
// Distance mimics numpy order: (x_norm + c_norm) - 2*dot, sequential-d
// accumulation, ascending-k strict '<' scan (ties -> lowest k, like
// np.argmin).

#define NTOK   16384
#define DMODEL 512
#define NGRP   8
#define DG     64
#define NCODE  1024

__global__ __launch_bounds__(512, 4) void vq_fp32_kernel(
    const float* __restrict__ x,
    const float* __restrict__ cb,
    float* __restrict__ out)
{
    __shared__ float cn[NGRP][NCODE];   // 32 KB

    const int tid  = threadIdx.x;
    const int lane = tid & 63;
    const int wave = tid >> 6;                       // 0..7
    const int g    = __builtin_amdgcn_readfirstlane(wave);
    const int token = blockIdx.x * 64 + lane;

    const float* __restrict__ cbg = cb + (size_t)g * NCODE * DG;

    // --- per-wave c_norm for this wave's group into LDS (once) ---
    for (int kk = lane; kk < NCODE; kk += 64) {
        const float4* c4 = reinterpret_cast<const float4*>(cbg + kk * DG);
        float s = 0.0f;
        #pragma unroll
        for (int j = 0; j < 16; ++j) {
            float4 v = c4[j];
            s = fmaf(v.x, v.x, s);
            s = fmaf(v.y, v.y, s);
            s = fmaf(v.z, v.z, s);
            s = fmaf(v.w, v.w, s);
        }
        cn[g][kk] = s;
    }
    __syncthreads();

    // --- load this thread's x segment into registers ---
    float4 xv[16];
    const float4* xp = reinterpret_cast<const float4*>(
        x + (size_t)token * DMODEL + g * DG);
    #pragma unroll
    for (int j = 0; j < 16; ++j) xv[j] = xp[j];

    float xn = 0.0f;
    #pragma unroll
    for (int j = 0; j < 16; ++j) {
        xn = fmaf(xv[j].x, xv[j].x, xn);
        xn = fmaf(xv[j].y, xv[j].y, xn);
        xn = fmaf(xv[j].z, xv[j].z, xn);
        xn = fmaf(xv[j].w, xv[j].w, xn);
    }

    // --- scan all 1024 codes of this group ---
    float best = 3.4e38f;
    int   bidx = 0;
    for (int k = 0; k < NCODE; ++k) {
        const float4* c4 = reinterpret_cast<const float4*>(cbg + k * DG);
        float dot = 0.0f;
        #pragma unroll
        for (int j = 0; j < 16; ++j) {
            float4 v = c4[j];   // wave-uniform address -> s_load
            dot = fmaf(xv[j].x, v.x, dot);
            dot = fmaf(xv[j].y, v.y, dot);
            dot = fmaf(xv[j].z, v.z, dot);
            dot = fmaf(xv[j].w, v.w, dot);
        }
        float t    = xn + cn[g][k];
        float dist = t - 2.0f * dot;
        if (dist < best) { best = dist; bidx = k; }   // strict <: lowest k wins ties
    }

    // --- write the selected code row ---
    const float4* q4 = reinterpret_cast<const float4*>(cbg + bidx * DG);
    float4* o4 = reinterpret_cast<float4*>(out + (size_t)token * DMODEL + g * DG);
    #pragma unroll
    for (int j = 0; j < 16; ++j) o4[j] = q4[j];
}

extern "C" void kernel_launch(void* const* d_in, const int* in_sizes, int n_in,
                              void* d_out, int out_size, void* d_ws, size_t ws_size,
                              hipStream_t stream) {
    const float* x  = (const float*)d_in[0];   // 8*2048*512
    const float* cb = (const float*)d_in[1];   // 8*1024*64
    float* out = (float*)d_out;

    // 16384 tokens / 64 tokens-per-block = 256 blocks of 512 threads
    vq_fp32_kernel<<<256, 512, 0, stream>>>(x, cb, out);
}

// Round 2
// 142.378 us; speedup vs baseline: 3.4069x; 3.4069x over previous
//
#include <hip/hip_runtime.h>

// Grouped VQ via bf16 MFMA screen + exact-fp32 rescue.
// x: [8,2048,512] f32, codebook: [8,1024,64] f32, out = selected code rows.
//
// Screen: dist_partial[k] = c_norm[k] - 2 * <x, c_k>  (x_norm is constant per
// token -> irrelevant for argmin). Cross terms via mfma_f32_16x16x32_bf16.
// Rescue: any code with screened dist <= min + EPS is recomputed exactly in
// fp32 reference order; lowest index wins ties. EPS=0.08 > 2x worst-case
// bf16 screen error (~0.034).

#define NTOK   16384
#define DMODEL 512
#define NGRP   8
#define DG     64
#define NCODE  1024
#define EPS    0.08f

typedef __attribute__((ext_vector_type(8))) __bf16 bf16x8;
typedef __attribute__((ext_vector_type(4))) float  f32x4;

// ---------------- prep: pack codebook into B-fragment layout (bf16) --------
// ws_b element index = (((g*64 + ct)*2 + s)*64 + lane)*8 + j
//   holds cb[g][ct*16 + (lane&15)][s*32 + (lane>>4)*8 + j] as bf16.
__global__ __launch_bounds__(256) void prep_frags(
    const float* __restrict__ cb, __bf16* __restrict__ wb)
{
    int tid  = blockIdx.x * 256 + threadIdx.x;      // 0..65535
    int lane = tid & 63;
    int s    = (tid >> 6) & 1;
    int ct   = (tid >> 7) & 63;
    int g    = tid >> 13;
    int code = ct * 16 + (lane & 15);
    int k0   = s * 32 + (lane >> 4) * 8;
    const float* src = cb + ((size_t)g * NCODE + code) * DG + k0;
    bf16x8 v;
    #pragma unroll
    for (int j = 0; j < 8; ++j) v[j] = (__bf16)src[j];
    *reinterpret_cast<bf16x8*>(wb + (size_t)tid * 8) = v;
}

// c_norm fp32, same accumulation order as the reference-faithful baseline.
__global__ __launch_bounds__(256) void prep_cnorm(
    const float* __restrict__ cb, float* __restrict__ wcn)
{
    int i = blockIdx.x * 256 + threadIdx.x;         // 0..8191 (g*1024+code)
    const float4* c4 = reinterpret_cast<const float4*>(cb + (size_t)i * DG);
    float s = 0.0f;
    #pragma unroll
    for (int j = 0; j < 16; ++j) {
        float4 v = c4[j];
        s = fmaf(v.x, v.x, s); s = fmaf(v.y, v.y, s);
        s = fmaf(v.z, v.z, s); s = fmaf(v.w, v.w, s);
    }
    wcn[i] = s;
}

__device__ __forceinline__ float dot64(const float* __restrict__ a,
                                       const float* __restrict__ b)
{
    const float4* a4 = reinterpret_cast<const float4*>(a);
    const float4* b4 = reinterpret_cast<const float4*>(b);
    float s = 0.0f;
    #pragma unroll
    for (int j = 0; j < 16; ++j) {
        float4 u = a4[j], v = b4[j];
        s = fmaf(u.x, v.x, s); s = fmaf(u.y, v.y, s);
        s = fmaf(u.z, v.z, s); s = fmaf(u.w, v.w, s);
    }
    return s;
}

// ---------------- main: screen + rescue ------------------------------------
// Block = 256 threads (4 waves). Block handles 64 tokens x 1 group.
// Wave w: tokens tile*64 + w*16 .. +16. Group = blockIdx.x & 7 (L2 reuse of x).
__global__ __launch_bounds__(256, 8) void vq_mfma_kernel(
    const float*  __restrict__ x,
    const float*  __restrict__ cb,
    const __bf16* __restrict__ wb,
    const float*  __restrict__ wcn,
    float* __restrict__ out)
{
    __shared__ float cn[NCODE];

    const int tid  = threadIdx.x;
    const int lane = tid & 63;
    const int w    = tid >> 6;
    const int g    = blockIdx.x & 7;
    const int tile = blockIdx.x >> 3;

    // stage c_norm for this group (1024 floats)
    reinterpret_cast<float4*>(cn)[tid] =
        reinterpret_cast<const float4*>(wcn + g * NCODE)[tid];
    __syncthreads();

    // A fragments: row = lane&15 (token), k = s*32 + (lane>>4)*8 + j
    const int ta = tile * 64 + w * 16 + (lane & 15);
    const int k0 = (lane >> 4) * 8;
    const float* xrow = x + (size_t)ta * DMODEL + g * DG;
    bf16x8 a0, a1;
    #pragma unroll
    for (int j = 0; j < 8; ++j) a0[j] = (__bf16)xrow[k0 + j];
    #pragma unroll
    for (int j = 0; j < 8; ++j) a1[j] = (__bf16)xrow[32 + k0 + j];

    const __bf16* wbg = wb + (size_t)g * (64 * 2 * 64 * 8);

    float best[4], sec[4];
    int   bidx_[4], sidx[4];
    #pragma unroll
    for (int r = 0; r < 4; ++r) {
        best[r] = 1e30f; sec[r] = 1e30f;
        bidx_[r] = 0x7fffffff; sidx[r] = 0x7fffffff;
    }

    for (int ct = 0; ct < 64; ++ct) {
        bf16x8 b0 = *reinterpret_cast<const bf16x8*>(wbg + ((size_t)(ct * 2 + 0) * 64 + lane) * 8);
        bf16x8 b1 = *reinterpret_cast<const bf16x8*>(wbg + ((size_t)(ct * 2 + 1) * 64 + lane) * 8);
        f32x4 d = {0.0f, 0.0f, 0.0f, 0.0f};
        d = __builtin_amdgcn_mfma_f32_16x16x32_bf16(a0, b0, d, 0, 0, 0);
        d = __builtin_amdgcn_mfma_f32_16x16x32_bf16(a1, b1, d, 0, 0, 0);
        const int code = ct * 16 + (lane & 15);
        const float cnv = cn[code];
        #pragma unroll
        for (int r = 0; r < 4; ++r) {
            float sd = fmaf(-2.0f, d[r], cnv);
            if (sd < best[r]) {
                sec[r] = best[r]; sidx[r] = bidx_[r];
                best[r] = sd;     bidx_[r] = code;
            } else if (sd < sec[r]) {
                sec[r] = sd; sidx[r] = code;
            }
        }
    }

    // min+index reduce across the 16-lane col-group (tie -> lowest index)
    float m[4]; int mi[4];
    #pragma unroll
    for (int r = 0; r < 4; ++r) { m[r] = best[r]; mi[r] = bidx_[r]; }
    #pragma unroll
    for (int mask = 1; mask < 16; mask <<= 1) {
        #pragma unroll
        for (int r = 0; r < 4; ++r) {
            float pm = __shfl_xor(m[r], mask, 64);
            int   pi = __shfl_xor(mi[r], mask, 64);
            if (pm < m[r] || (pm == m[r] && pi < mi[r])) { m[r] = pm; mi[r] = pi; }
        }
    }

    const int lg = lane >> 4;
    const float* cbg = cb + (size_t)g * NCODE * DG;
    int fidx[4];

    #pragma unroll 1
    for (int r = 0; r < 4; ++r) {
        const float thr = m[r] + EPS;
        bool oth = (best[r] <= thr && bidx_[r] != mi[r]) || (sec[r] <= thr);
        unsigned long long bal = __ballot(oth);
        bool need = ((bal >> (lg * 16)) & 0xffffULL) != 0ULL;
        if (!need) { fidx[r] = mi[r]; continue; }

        // exact fp32 rescue over tracked candidates within threshold
        const int token = tile * 64 + w * 16 + lg * 4 + r;
        const float* xr = x + (size_t)token * DMODEL + g * DG;
        const float xn = dot64(xr, xr);
        float ed = 1e30f; int ei = 0x7fffffff;
        if (best[r] <= thr) {
            int c = bidx_[r];
            float dd = (xn + cn[c]) - 2.0f * dot64(xr, cbg + (size_t)c * DG);
            if (dd < ed || (dd == ed && c < ei)) { ed = dd; ei = c; }
        }
        if (sec[r] <= thr) {
            int c = sidx[r];
            float dd = (xn + cn[c]) - 2.0f * dot64(xr, cbg + (size_t)c * DG);
            if (dd < ed || (dd == ed && c < ei)) { ed = dd; ei = c; }
        }
        #pragma unroll
        for (int mask = 1; mask < 16; mask <<= 1) {
            float pd = __shfl_xor(ed, mask, 64);
            int   pi = __shfl_xor(ei, mask, 64);
            if (pd < ed || (pd == ed && pi < ei)) { ed = pd; ei = pi; }
        }
        fidx[r] = ei;
    }

    // write selected code rows: group's 16 lanes copy 4 rows (float4 each)
    const int sub = lane & 15;
    #pragma unroll
    for (int r = 0; r < 4; ++r) {
        const int token = tile * 64 + w * 16 + lg * 4 + r;
        const float4* src = reinterpret_cast<const float4*>(cbg + (size_t)fidx[r] * DG);
        float4* dst = reinterpret_cast<float4*>(out + (size_t)token * DMODEL + g * DG);
        dst[sub] = src[sub];
    }
}

// ---------------- fp32 fallback (ws too small) -----------------------------
__global__ __launch_bounds__(512, 4) void vq_fp32_kernel(
    const float* __restrict__ x,
    const float* __restrict__ cb,
    float* __restrict__ out)
{
    __shared__ float cnl[NGRP][NCODE];
    const int tid  = threadIdx.x;
    const int lane = tid & 63;
    const int wave = tid >> 6;
    const int g    = __builtin_amdgcn_readfirstlane(wave);
    const int token = blockIdx.x * 64 + lane;
    const float* __restrict__ cbg = cb + (size_t)g * NCODE * DG;

    for (int kk = lane; kk < NCODE; kk += 64) {
        const float4* c4 = reinterpret_cast<const float4*>(cbg + kk * DG);
        float s = 0.0f;
        #pragma unroll
        for (int j = 0; j < 16; ++j) {
            float4 v = c4[j];
            s = fmaf(v.x, v.x, s); s = fmaf(v.y, v.y, s);
            s = fmaf(v.z, v.z, s); s = fmaf(v.w, v.w, s);
        }
        cnl[g][kk] = s;
    }
    __syncthreads();

    const float* xr = x + (size_t)token * DMODEL + g * DG;
    float xn = dot64(xr, xr);
    float bestv = 3.4e38f; int bidx = 0;
    for (int k = 0; k < NCODE; ++k) {
        float dist = (xn + cnl[g][k]) - 2.0f * dot64(xr, cbg + (size_t)k * DG);
        if (dist < bestv) { bestv = dist; bidx = k; }
    }
    const float4* q4 = reinterpret_cast<const float4*>(cbg + (size_t)bidx * DG);
    float4* o4 = reinterpret_cast<float4*>(out + (size_t)token * DMODEL + g * DG);
    #pragma unroll
    for (int j = 0; j < 16; ++j) o4[j] = q4[j];
}

extern "C" void kernel_launch(void* const* d_in, const int* in_sizes, int n_in,
                              void* d_out, int out_size, void* d_ws, size_t ws_size,
                              hipStream_t stream) {
    const float* x  = (const float*)d_in[0];
    const float* cb = (const float*)d_in[1];
    float* out = (float*)d_out;

    const size_t wb_bytes = (size_t)NGRP * NCODE * DG * sizeof(__bf16); // 1 MB
    const size_t cn_bytes = (size_t)NGRP * NCODE * sizeof(float);       // 32 KB
    if (ws_size < wb_bytes + cn_bytes) {
        vq_fp32_kernel<<<256, 512, 0, stream>>>(x, cb, out);
        return;
    }
    __bf16* wb  = (__bf16*)d_ws;
    float*  wcn = (float*)((char*)d_ws + wb_bytes);

    prep_frags<<<256, 256, 0, stream>>>(cb, wb);   // 65536 threads
    prep_cnorm<<<32, 256, 0, stream>>>(cb, wcn);   // 8192 threads
    vq_mfma_kernel<<<NTOK / 64 * NGRP, 256, 0, stream>>>(x, cb, wb, wcn, out);
}

// Round 3
// 87.906 us; speedup vs baseline: 5.5181x; 1.6197x over previous
//
#include <hip/hip_runtime.h>

// Grouped VQ: bf16-MFMA screen + exact-fp32 rescue, v3.
// - 64 tokens per wave (4 A-subtiles) -> 2 b-loads feed 8 MFMAs per iter
// - branch-free software prefetch of next b-fragments
// - packed sortable uint keys (dist|code) -> 5 VALU ops per distance,
//   lowest-index tie-break for free
// Screen quantity: sd = (cn + 64) - 2*<x,c>_bf16  (positive: |2 dot| << 64),
// truncated to 22 high bits + 10-bit code. EPS=0.10 covers 2*(bf16 0.031 +
// trunc 0.008). Rescue recomputes exact fp32 dists in reference order.

#define NTOK   16384
#define DMODEL 512
#define NGRP   8
#define DG     64
#define NCODE  1024
#define EPS    0.10f

typedef __attribute__((ext_vector_type(8))) __bf16 bf16x8;
typedef __attribute__((ext_vector_type(4))) float  f32x4;

__device__ __forceinline__ unsigned umin_(unsigned a, unsigned b){ return a<b?a:b; }
__device__ __forceinline__ unsigned umax_(unsigned a, unsigned b){ return a>b?a:b; }

// ---------------- prep: pack codebook into B-fragment layout (bf16) --------
// ws_b element index = (((g*64 + ct)*2 + s)*64 + lane)*8 + j
//   holds cb[g][ct*16 + (lane&15)][s*32 + (lane>>4)*8 + j] as bf16.
__global__ __launch_bounds__(256) void prep_frags(
    const float* __restrict__ cb, __bf16* __restrict__ wb)
{
    int tid  = blockIdx.x * 256 + threadIdx.x;      // 0..65535
    int lane = tid & 63;
    int s    = (tid >> 6) & 1;
    int ct   = (tid >> 7) & 63;
    int g    = tid >> 13;
    int code = ct * 16 + (lane & 15);
    int k0   = s * 32 + (lane >> 4) * 8;
    const float* src = cb + ((size_t)g * NCODE + code) * DG + k0;
    bf16x8 v;
    #pragma unroll
    for (int j = 0; j < 8; ++j) v[j] = (__bf16)src[j];
    *reinterpret_cast<bf16x8*>(wb + (size_t)tid * 8) = v;
}

__global__ __launch_bounds__(256) void prep_cnorm(
    const float* __restrict__ cb, float* __restrict__ wcn)
{
    int i = blockIdx.x * 256 + threadIdx.x;         // 0..8191 (g*1024+code)
    const float4* c4 = reinterpret_cast<const float4*>(cb + (size_t)i * DG);
    float s = 0.0f;
    #pragma unroll
    for (int j = 0; j < 16; ++j) {
        float4 v = c4[j];
        s = fmaf(v.x, v.x, s); s = fmaf(v.y, v.y, s);
        s = fmaf(v.z, v.z, s); s = fmaf(v.w, v.w, s);
    }
    wcn[i] = s;
}

__device__ __forceinline__ float dotc(const float* __restrict__ a,
                                      const float* __restrict__ b)
{
    const float4* a4 = reinterpret_cast<const float4*>(a);
    const float4* b4 = reinterpret_cast<const float4*>(b);
    float s = 0.0f;
    #pragma unroll 4
    for (int j = 0; j < 16; ++j) {
        float4 u = a4[j], v = b4[j];
        s = fmaf(u.x, v.x, s); s = fmaf(u.y, v.y, s);
        s = fmaf(u.z, v.z, s); s = fmaf(u.w, v.w, s);
    }
    return s;
}

__device__ __forceinline__ bf16x8 cvt8(const float* __restrict__ p)
{
    float4 u = *reinterpret_cast<const float4*>(p);
    float4 v = *reinterpret_cast<const float4*>(p + 4);
    bf16x8 r;
    r[0]=(__bf16)u.x; r[1]=(__bf16)u.y; r[2]=(__bf16)u.z; r[3]=(__bf16)u.w;
    r[4]=(__bf16)v.x; r[5]=(__bf16)v.y; r[6]=(__bf16)v.z; r[7]=(__bf16)v.w;
    return r;
}

// ---------------- main: screen + rescue ------------------------------------
// Block = 256 threads (4 waves). Wave handles 64 tokens x 1 group.
// Grid = 64 tiles * 8 groups; group = blockIdx.x & 7.
__global__ __launch_bounds__(256, 2) void vq_mfma_kernel(
    const float*  __restrict__ x,
    const float*  __restrict__ cb,
    const __bf16* __restrict__ wb,
    const float*  __restrict__ wcn,
    float* __restrict__ out)
{
    __shared__ float cn64[NCODE];

    const int tid  = threadIdx.x;
    const int lane = tid & 63;
    const int w    = tid >> 6;
    const int g    = blockIdx.x & 7;
    const int tile = blockIdx.x >> 3;

    {   // stage cn+64 for the screen (rescue uses true wcn from L2)
        float4 v = reinterpret_cast<const float4*>(wcn + g * NCODE)[tid];
        v.x += 64.0f; v.y += 64.0f; v.z += 64.0f; v.w += 64.0f;
        reinterpret_cast<float4*>(cn64)[tid] = v;
    }
    __syncthreads();

    const int row  = lane & 15;
    const int q    = lane >> 4;
    const int k0   = q * 8;
    const int tok0 = tile * 256 + w * 64;

    // A fragments for 4 token-subtiles: row=lane&15, k = q*8+j (+32 for aB)
    bf16x8 aA[4], aB[4];
    #pragma unroll
    for (int s = 0; s < 4; ++s) {
        const float* xr = x + (size_t)(tok0 + s * 16 + row) * DMODEL + g * DG;
        aA[s] = cvt8(xr + k0);
        aB[s] = cvt8(xr + 32 + k0);
    }

    unsigned best[4][4], sec[4][4];
    #pragma unroll
    for (int s = 0; s < 4; ++s)
        #pragma unroll
        for (int r = 0; r < 4; ++r) { best[s][r] = 0xFFFFFFFFu; sec[s][r] = 0xFFFFFFFFu; }

    const __bf16* wbg = wb + (size_t)g * (NCODE * DG);
    bf16x8 b0 = *reinterpret_cast<const bf16x8*>(wbg + ((size_t)0 * 64 + lane) * 8);
    bf16x8 b1 = *reinterpret_cast<const bf16x8*>(wbg + ((size_t)1 * 64 + lane) * 8);

    for (int ct = 0; ct < 64; ++ct) {
        const int nct = (ct + 1) & 63;   // wraps: harmless reload of ct=0
        bf16x8 n0 = *reinterpret_cast<const bf16x8*>(wbg + ((size_t)(nct * 2 + 0) * 64 + lane) * 8);
        bf16x8 n1 = *reinterpret_cast<const bf16x8*>(wbg + ((size_t)(nct * 2 + 1) * 64 + lane) * 8);

        f32x4 d[4];
        #pragma unroll
        for (int s = 0; s < 4; ++s) {
            f32x4 z = {0.0f, 0.0f, 0.0f, 0.0f};
            z = __builtin_amdgcn_mfma_f32_16x16x32_bf16(aA[s], b0, z, 0, 0, 0);
            d[s] = __builtin_amdgcn_mfma_f32_16x16x32_bf16(aB[s], b1, z, 0, 0, 0);
        }

        const int code = ct * 16 + row;
        const float cnv = cn64[code];
        #pragma unroll
        for (int s = 0; s < 4; ++s) {
            #pragma unroll
            for (int r = 0; r < 4; ++r) {
                float sd = fmaf(-2.0f, d[s][r], cnv);      // positive by construction
                unsigned key = (__float_as_uint(sd) & 0xFFFFFC00u) | (unsigned)code;
                unsigned bo  = best[s][r];
                best[s][r] = umin_(bo, key);
                sec[s][r]  = umin_(sec[s][r], umax_(bo, key));
            }
        }
        b0 = n0; b1 = n1;
    }

    // min-reduce packed keys across each 16-lane col group (q-group)
    unsigned mk[4][4];
    #pragma unroll
    for (int s = 0; s < 4; ++s)
        #pragma unroll
        for (int r = 0; r < 4; ++r) mk[s][r] = best[s][r];
    #pragma unroll
    for (int mask = 1; mask < 16; mask <<= 1) {
        #pragma unroll
        for (int s = 0; s < 4; ++s)
            #pragma unroll
            for (int r = 0; r < 4; ++r) {
                unsigned o = (unsigned)__shfl_xor((int)mk[s][r], mask, 64);
                mk[s][r] = umin_(mk[s][r], o);
            }
    }

    const float* cbg  = cb  + (size_t)g * NCODE * DG;
    const float* wcng = wcn + (size_t)g * NCODE;

    #pragma unroll
    for (int s = 0; s < 4; ++s) {
        #pragma unroll
        for (int r = 0; r < 4; ++r) {
            const unsigned m_ = mk[s][r];
            int sel = (int)(m_ & 0x3FFu);
            const float thr = __uint_as_float(m_ & 0xFFFFFC00u) + EPS;
            const float bd  = __uint_as_float(best[s][r] & 0xFFFFFC00u);
            const float sdd = __uint_as_float(sec[s][r]  & 0xFFFFFC00u);
            const bool oth = (bd <= thr && best[s][r] != m_) || (sdd <= thr);
            const unsigned long long bal = __ballot(oth);
            if (((bal >> (q * 16)) & 0xFFFFULL) != 0ULL) {
                // exact fp32 rescue among tracked candidates
                const int token = tok0 + s * 16 + q * 4 + r;
                const float* xr = x + (size_t)token * DMODEL + g * DG;
                const float xn = dotc(xr, xr);
                float ed = 1e30f; int ei = 0x7FFFFFFF;
                if (bd <= thr) {
                    const int c = (int)(best[s][r] & 0x3FFu);
                    float dd = (xn + wcng[c]) - 2.0f * dotc(xr, cbg + (size_t)c * DG);
                    if (dd < ed || (dd == ed && c < ei)) { ed = dd; ei = c; }
                }
                if (sdd <= thr) {
                    const int c = (int)(sec[s][r] & 0x3FFu);
                    float dd = (xn + wcng[c]) - 2.0f * dotc(xr, cbg + (size_t)c * DG);
                    if (dd < ed || (dd == ed && c < ei)) { ed = dd; ei = c; }
                }
                #pragma unroll
                for (int mask = 1; mask < 16; mask <<= 1) {
                    float pd = __shfl_xor(ed, mask, 64);
                    int   pi = __shfl_xor(ei, mask, 64);
                    if (pd < ed || (pd == ed && pi < ei)) { ed = pd; ei = pi; }
                }
                sel = ei;
            }
            // write the selected code row (16 lanes x float4 = 64 floats)
            const int token = tok0 + s * 16 + q * 4 + r;
            const float4 src = reinterpret_cast<const float4*>(cbg + (size_t)sel * DG)[row];
            reinterpret_cast<float4*>(out + (size_t)token * DMODEL + g * DG)[row] = src;
        }
    }
}

// ---------------- fp32 fallback (ws too small) -----------------------------
__global__ __launch_bounds__(512, 4) void vq_fp32_kernel(
    const float* __restrict__ x,
    const float* __restrict__ cb,
    float* __restrict__ out)
{
    __shared__ float cnl[NGRP][NCODE];
    const int tid  = threadIdx.x;
    const int lane = tid & 63;
    const int wave = tid >> 6;
    const int g    = __builtin_amdgcn_readfirstlane(wave);
    const int token = blockIdx.x * 64 + lane;
    const float* __restrict__ cbg = cb + (size_t)g * NCODE * DG;

    for (int kk = lane; kk < NCODE; kk += 64) {
        const float4* c4 = reinterpret_cast<const float4*>(cbg + kk * DG);
        float s = 0.0f;
        #pragma unroll
        for (int j = 0; j < 16; ++j) {
            float4 v = c4[j];
            s = fmaf(v.x, v.x, s); s = fmaf(v.y, v.y, s);
            s = fmaf(v.z, v.z, s); s = fmaf(v.w, v.w, s);
        }
        cnl[g][kk] = s;
    }
    __syncthreads();

    const float* xr = x + (size_t)token * DMODEL + g * DG;
    float xn = dotc(xr, xr);
    float bestv = 3.4e38f; int bidx = 0;
    for (int k = 0; k < NCODE; ++k) {
        float dist = (xn + cnl[g][k]) - 2.0f * dotc(xr, cbg + (size_t)k * DG);
        if (dist < bestv) { bestv = dist; bidx = k; }
    }
    const float4* q4 = reinterpret_cast<const float4*>(cbg + (size_t)bidx * DG);
    float4* o4 = reinterpret_cast<float4*>(out + (size_t)token * DMODEL + g * DG);
    #pragma unroll
    for (int j = 0; j < 16; ++j) o4[j] = q4[j];
}

extern "C" void kernel_launch(void* const* d_in, const int* in_sizes, int n_in,
                              void* d_out, int out_size, void* d_ws, size_t ws_size,
                              hipStream_t stream) {
    const float* x  = (const float*)d_in[0];
    const float* cb = (const float*)d_in[1];
    float* out = (float*)d_out;

    const size_t wb_bytes = (size_t)NGRP * NCODE * DG * sizeof(__bf16); // 1 MB
    const size_t cn_bytes = (size_t)NGRP * NCODE * sizeof(float);       // 32 KB
    if (ws_size < wb_bytes + cn_bytes) {
        vq_fp32_kernel<<<256, 512, 0, stream>>>(x, cb, out);
        return;
    }
    __bf16* wb  = (__bf16*)d_ws;
    float*  wcn = (float*)((char*)d_ws + wb_bytes);

    prep_frags<<<256, 256, 0, stream>>>(cb, wb);
    prep_cnorm<<<32, 256, 0, stream>>>(cb, wcn);
    vq_mfma_kernel<<<512, 256, 0, stream>>>(x, cb, wb, wcn, out);
}

// Round 4
// 72.380 us; speedup vs baseline: 6.7018x; 1.2145x over previous
//
#include <hip/hip_runtime.h>

// Grouped VQ: bf16-MFMA screen + exact-fp32 rescue, v4.
// vs v3: 32 tokens/wave (2 subtiles) -> grid 1024 (16 waves/CU, 4/SIMD),
// launch_bounds(256,4) caps VGPR at 128 so best/sec stay in VGPRs (v3's
// VGPR_Count=60 showed AGPR banking + v_accvgpr shuffle inflation).
// Manual 2x unroll with two NAMED b-register sets -> prefetch distance 2.
// Numerics identical to v3 (passed): screen sd=(cn+64)-2*dot_bf16 packed to
// 22-bit key | 10-bit code, EPS=0.10, exact-fp32 rescue in reference order.

#define NTOK   16384
#define DMODEL 512
#define NGRP   8
#define DG     64
#define NCODE  1024
#define EPS    0.10f

typedef __attribute__((ext_vector_type(8))) __bf16 bf16x8;
typedef __attribute__((ext_vector_type(4))) float  f32x4;

__device__ __forceinline__ unsigned umin_(unsigned a, unsigned b){ return a<b?a:b; }
__device__ __forceinline__ unsigned umax_(unsigned a, unsigned b){ return a>b?a:b; }

// ---------------- prep: pack codebook into B-fragment layout (bf16) --------
// ws_b element index = (((g*64 + ct)*2 + s)*64 + lane)*8 + j
//   holds cb[g][ct*16 + (lane&15)][s*32 + (lane>>4)*8 + j] as bf16.
__global__ __launch_bounds__(256) void prep_frags(
    const float* __restrict__ cb, __bf16* __restrict__ wb)
{
    int tid  = blockIdx.x * 256 + threadIdx.x;      // 0..65535
    int lane = tid & 63;
    int s    = (tid >> 6) & 1;
    int ct   = (tid >> 7) & 63;
    int g    = tid >> 13;
    int code = ct * 16 + (lane & 15);
    int k0   = s * 32 + (lane >> 4) * 8;
    const float* src = cb + ((size_t)g * NCODE + code) * DG + k0;
    bf16x8 v;
    #pragma unroll
    for (int j = 0; j < 8; ++j) v[j] = (__bf16)src[j];
    *reinterpret_cast<bf16x8*>(wb + (size_t)tid * 8) = v;
}

__global__ __launch_bounds__(256) void prep_cnorm(
    const float* __restrict__ cb, float* __restrict__ wcn)
{
    int i = blockIdx.x * 256 + threadIdx.x;         // 0..8191 (g*1024+code)
    const float4* c4 = reinterpret_cast<const float4*>(cb + (size_t)i * DG);
    float s = 0.0f;
    #pragma unroll
    for (int j = 0; j < 16; ++j) {
        float4 v = c4[j];
        s = fmaf(v.x, v.x, s); s = fmaf(v.y, v.y, s);
        s = fmaf(v.z, v.z, s); s = fmaf(v.w, v.w, s);
    }
    wcn[i] = s;
}

__device__ __forceinline__ float dotc(const float* __restrict__ a,
                                      const float* __restrict__ b)
{
    const float4* a4 = reinterpret_cast<const float4*>(a);
    const float4* b4 = reinterpret_cast<const float4*>(b);
    float s = 0.0f;
    #pragma unroll 4
    for (int j = 0; j < 16; ++j) {
        float4 u = a4[j], v = b4[j];
        s = fmaf(u.x, v.x, s); s = fmaf(u.y, v.y, s);
        s = fmaf(u.z, v.z, s); s = fmaf(u.w, v.w, s);
    }
    return s;
}

__device__ __forceinline__ bf16x8 cvt8(const float* __restrict__ p)
{
    float4 u = *reinterpret_cast<const float4*>(p);
    float4 v = *reinterpret_cast<const float4*>(p + 4);
    bf16x8 r;
    r[0]=(__bf16)u.x; r[1]=(__bf16)u.y; r[2]=(__bf16)u.z; r[3]=(__bf16)u.w;
    r[4]=(__bf16)v.x; r[5]=(__bf16)v.y; r[6]=(__bf16)v.z; r[7]=(__bf16)v.w;
    return r;
}

__device__ __forceinline__ bf16x8 ldfrag(const __bf16* __restrict__ wbg,
                                         int ct, int shalf, int lane)
{
    return *reinterpret_cast<const bf16x8*>(
        wbg + ((size_t)(ct * 2 + shalf) * 64 + lane) * 8);
}

// ---------------- main: screen + rescue ------------------------------------
// Block = 256 threads (4 waves). Wave handles 32 tokens x 1 group.
// Grid = 128 tiles * 8 groups = 1024 blocks (4/CU -> 16 waves/CU).
__global__ __launch_bounds__(256, 4) void vq_mfma_kernel(
    const float*  __restrict__ x,
    const float*  __restrict__ cb,
    const __bf16* __restrict__ wb,
    const float*  __restrict__ wcn,
    float* __restrict__ out)
{
    __shared__ float cn64[NCODE];

    const int tid  = threadIdx.x;
    const int lane = tid & 63;
    const int w    = tid >> 6;
    const int g    = blockIdx.x & 7;
    const int tile = blockIdx.x >> 3;

    {   // stage cn+64 for the screen (rescue uses true wcn from L2)
        float4 v = reinterpret_cast<const float4*>(wcn + g * NCODE)[tid];
        v.x += 64.0f; v.y += 64.0f; v.z += 64.0f; v.w += 64.0f;
        reinterpret_cast<float4*>(cn64)[tid] = v;
    }
    __syncthreads();

    const int row  = lane & 15;
    const int q    = lane >> 4;
    const int k0   = q * 8;
    const int tok0 = tile * 128 + w * 32;

    // A fragments for 2 token-subtiles: row=lane&15, k = q*8+j (+32 for aB)
    bf16x8 aA[2], aB[2];
    #pragma unroll
    for (int s = 0; s < 2; ++s) {
        const float* xr = x + (size_t)(tok0 + s * 16 + row) * DMODEL + g * DG;
        aA[s] = cvt8(xr + k0);
        aB[s] = cvt8(xr + 32 + k0);
    }

    unsigned best[2][4], sec[2][4];
    #pragma unroll
    for (int s = 0; s < 2; ++s)
        #pragma unroll
        for (int r = 0; r < 4; ++r) { best[s][r] = 0xFFFFFFFFu; sec[s][r] = 0xFFFFFFFFu; }

    const __bf16* wbg = wb + (size_t)g * (NCODE * DG);

    // two named b-register sets -> prefetch distance 2 (no runtime-indexed arrays)
    bf16x8 b0a = ldfrag(wbg, 0, 0, lane), b1a = ldfrag(wbg, 0, 1, lane);
    bf16x8 b0b = ldfrag(wbg, 1, 0, lane), b1b = ldfrag(wbg, 1, 1, lane);

    for (int ct = 0; ct < 64; ct += 2) {
        // ---- tile ct (a-set) ----
        {
            f32x4 d[2];
            #pragma unroll
            for (int s = 0; s < 2; ++s) {
                f32x4 z = {0.0f, 0.0f, 0.0f, 0.0f};
                z = __builtin_amdgcn_mfma_f32_16x16x32_bf16(aA[s], b0a, z, 0, 0, 0);
                d[s] = __builtin_amdgcn_mfma_f32_16x16x32_bf16(aB[s], b1a, z, 0, 0, 0);
            }
            const int nct = (ct + 2 < 64) ? (ct + 2) : 0;   // wrap: harmless reload
            b0a = ldfrag(wbg, nct, 0, lane);
            b1a = ldfrag(wbg, nct, 1, lane);
            const int code = ct * 16 + row;
            const float cnv = cn64[code];
            #pragma unroll
            for (int s = 0; s < 2; ++s)
                #pragma unroll
                for (int r = 0; r < 4; ++r) {
                    float sd = fmaf(-2.0f, d[s][r], cnv);   // positive by construction
                    unsigned key = (__float_as_uint(sd) & 0xFFFFFC00u) | (unsigned)code;
                    unsigned bo  = best[s][r];
                    best[s][r] = umin_(bo, key);
                    sec[s][r]  = umin_(sec[s][r], umax_(bo, key));
                }
        }
        // ---- tile ct+1 (b-set) ----
        {
            f32x4 d[2];
            #pragma unroll
            for (int s = 0; s < 2; ++s) {
                f32x4 z = {0.0f, 0.0f, 0.0f, 0.0f};
                z = __builtin_amdgcn_mfma_f32_16x16x32_bf16(aA[s], b0b, z, 0, 0, 0);
                d[s] = __builtin_amdgcn_mfma_f32_16x16x32_bf16(aB[s], b1b, z, 0, 0, 0);
            }
            const int nct = (ct + 3 < 64) ? (ct + 3) : 0;
            b0b = ldfrag(wbg, nct, 0, lane);
            b1b = ldfrag(wbg, nct, 1, lane);
            const int code = (ct + 1) * 16 + row;
            const float cnv = cn64[code];
            #pragma unroll
            for (int s = 0; s < 2; ++s)
                #pragma unroll
                for (int r = 0; r < 4; ++r) {
                    float sd = fmaf(-2.0f, d[s][r], cnv);
                    unsigned key = (__float_as_uint(sd) & 0xFFFFFC00u) | (unsigned)code;
                    unsigned bo  = best[s][r];
                    best[s][r] = umin_(bo, key);
                    sec[s][r]  = umin_(sec[s][r], umax_(bo, key));
                }
        }
    }

    // min-reduce packed keys across each 16-lane col group (q-group)
    unsigned mk[2][4];
    #pragma unroll
    for (int s = 0; s < 2; ++s)
        #pragma unroll
        for (int r = 0; r < 4; ++r) mk[s][r] = best[s][r];
    #pragma unroll
    for (int mask = 1; mask < 16; mask <<= 1) {
        #pragma unroll
        for (int s = 0; s < 2; ++s)
            #pragma unroll
            for (int r = 0; r < 4; ++r) {
                unsigned o = (unsigned)__shfl_xor((int)mk[s][r], mask, 64);
                mk[s][r] = umin_(mk[s][r], o);
            }
    }

    const float* cbg  = cb  + (size_t)g * NCODE * DG;
    const float* wcng = wcn + (size_t)g * NCODE;

    #pragma unroll
    for (int s = 0; s < 2; ++s) {
        #pragma unroll
        for (int r = 0; r < 4; ++r) {
            const unsigned m_ = mk[s][r];
            int sel = (int)(m_ & 0x3FFu);
            const float thr = __uint_as_float(m_ & 0xFFFFFC00u) + EPS;
            const float bd  = __uint_as_float(best[s][r] & 0xFFFFFC00u);
            const float sdd = __uint_as_float(sec[s][r]  & 0xFFFFFC00u);
            const bool oth = (bd <= thr && best[s][r] != m_) || (sdd <= thr);
            const unsigned long long bal = __ballot(oth);
            if (((bal >> (q * 16)) & 0xFFFFULL) != 0ULL) {
                // exact fp32 rescue among tracked candidates
                const int token = tok0 + s * 16 + q * 4 + r;
                const float* xr = x + (size_t)token * DMODEL + g * DG;
                const float xn = dotc(xr, xr);
                float ed = 1e30f; int ei = 0x7FFFFFFF;
                if (bd <= thr) {
                    const int c = (int)(best[s][r] & 0x3FFu);
                    float dd = (xn + wcng[c]) - 2.0f * dotc(xr, cbg + (size_t)c * DG);
                    if (dd < ed || (dd == ed && c < ei)) { ed = dd; ei = c; }
                }
                if (sdd <= thr) {
                    const int c = (int)(sec[s][r] & 0x3FFu);
                    float dd = (xn + wcng[c]) - 2.0f * dotc(xr, cbg + (size_t)c * DG);
                    if (dd < ed || (dd == ed && c < ei)) { ed = dd; ei = c; }
                }
                #pragma unroll
                for (int mask = 1; mask < 16; mask <<= 1) {
                    float pd = __shfl_xor(ed, mask, 64);
                    int   pi = __shfl_xor(ei, mask, 64);
                    if (pd < ed || (pd == ed && pi < ei)) { ed = pd; ei = pi; }
                }
                sel = ei;
            }
            // write the selected code row (16 lanes x float4 = 64 floats)
            const int token = tok0 + s * 16 + q * 4 + r;
            const float4 src = reinterpret_cast<const float4*>(cbg + (size_t)sel * DG)[row];
            reinterpret_cast<float4*>(out + (size_t)token * DMODEL + g * DG)[row] = src;
        }
    }
}

// ---------------- fp32 fallback (ws too small) -----------------------------
__global__ __launch_bounds__(512, 4) void vq_fp32_kernel(
    const float* __restrict__ x,
    const float* __restrict__ cb,
    float* __restrict__ out)
{
    __shared__ float cnl[NGRP][NCODE];
    const int tid  = threadIdx.x;
    const int lane = tid & 63;
    const int wave = tid >> 6;
    const int g    = __builtin_amdgcn_readfirstlane(wave);
    const int token = blockIdx.x * 64 + lane;
    const float* __restrict__ cbg = cb + (size_t)g * NCODE * DG;

    for (int kk = lane; kk < NCODE; kk += 64) {
        const float4* c4 = reinterpret_cast<const float4*>(cbg + kk * DG);
        float s = 0.0f;
        #pragma unroll
        for (int j = 0; j < 16; ++j) {
            float4 v = c4[j];
            s = fmaf(v.x, v.x, s); s = fmaf(v.y, v.y, s);
            s = fmaf(v.z, v.z, s); s = fmaf(v.w, v.w, s);
        }
        cnl[g][kk] = s;
    }
    __syncthreads();

    const float* xr = x + (size_t)token * DMODEL + g * DG;
    float xn = dotc(xr, xr);
    float bestv = 3.4e38f; int bidx = 0;
    for (int k = 0; k < NCODE; ++k) {
        float dist = (xn + cnl[g][k]) - 2.0f * dotc(xr, cbg + (size_t)k * DG);
        if (dist < bestv) { bestv = dist; bidx = k; }
    }
    const float4* q4 = reinterpret_cast<const float4*>(cbg + (size_t)bidx * DG);
    float4* o4 = reinterpret_cast<float4*>(out + (size_t)token * DMODEL + g * DG);
    #pragma unroll
    for (int j = 0; j < 16; ++j) o4[j] = q4[j];
}

extern "C" void kernel_launch(void* const* d_in, const int* in_sizes, int n_in,
                              void* d_out, int out_size, void* d_ws, size_t ws_size,
                              hipStream_t stream) {
    const float* x  = (const float*)d_in[0];
    const float* cb = (const float*)d_in[1];
    float* out = (float*)d_out;

    const size_t wb_bytes = (size_t)NGRP * NCODE * DG * sizeof(__bf16); // 1 MB
    const size_t cn_bytes = (size_t)NGRP * NCODE * sizeof(float);       // 32 KB
    if (ws_size < wb_bytes + cn_bytes) {
        vq_fp32_kernel<<<256, 512, 0, stream>>>(x, cb, out);
        return;
    }
    __bf16* wb  = (__bf16*)d_ws;
    float*  wcn = (float*)((char*)d_ws + wb_bytes);

    prep_frags<<<256, 256, 0, stream>>>(cb, wb);
    prep_cnorm<<<32, 256, 0, stream>>>(cb, wcn);
    vq_mfma_kernel<<<1024, 256, 0, stream>>>(x, cb, wb, wcn, out);
}

// Round 5
// 72.329 us; speedup vs baseline: 6.7065x; 1.0007x over previous
//
#include <hip/hip_runtime.h>

// Grouped VQ: bf16-MFMA screen + exact-fp32 rescue, v5.
// vs v4: (1) per-wave ct-phase stagger (off = ((tile+w)&3)*16) to break the
// lockstep load-wait convoy across co-resident waves; (2) wave-uniform
// (readfirstlane) ct indices -> scalar SADDR addressing for b-loads, no
// wrap-cndmask; (3) persistent zero C-operand (no per-ct accvgpr init).
// Numerics identical to v3/v4 (exact argmin): screen sd=(cn+64)-2*dot_bf16,
// 22-bit key | 10-bit code, EPS=0.10, exact-fp32 rescue in reference order.

#define NTOK   16384
#define DMODEL 512
#define NGRP   8
#define DG     64
#define NCODE  1024
#define EPS    0.10f

typedef __attribute__((ext_vector_type(8))) __bf16 bf16x8;
typedef __attribute__((ext_vector_type(4))) float  f32x4;

__device__ __forceinline__ unsigned umin_(unsigned a, unsigned b){ return a<b?a:b; }
__device__ __forceinline__ unsigned umax_(unsigned a, unsigned b){ return a>b?a:b; }

// ---------------- prep: pack codebook into B-fragment layout (bf16) --------
// ws_b element index = (((g*64 + ct)*2 + s)*64 + lane)*8 + j
//   holds cb[g][ct*16 + (lane&15)][s*32 + (lane>>4)*8 + j] as bf16.
__global__ __launch_bounds__(256) void prep_frags(
    const float* __restrict__ cb, __bf16* __restrict__ wb)
{
    int tid  = blockIdx.x * 256 + threadIdx.x;      // 0..65535
    int lane = tid & 63;
    int s    = (tid >> 6) & 1;
    int ct   = (tid >> 7) & 63;
    int g    = tid >> 13;
    int code = ct * 16 + (lane & 15);
    int k0   = s * 32 + (lane >> 4) * 8;
    const float* src = cb + ((size_t)g * NCODE + code) * DG + k0;
    bf16x8 v;
    #pragma unroll
    for (int j = 0; j < 8; ++j) v[j] = (__bf16)src[j];
    *reinterpret_cast<bf16x8*>(wb + (size_t)tid * 8) = v;
}

__global__ __launch_bounds__(256) void prep_cnorm(
    const float* __restrict__ cb, float* __restrict__ wcn)
{
    int i = blockIdx.x * 256 + threadIdx.x;         // 0..8191 (g*1024+code)
    const float4* c4 = reinterpret_cast<const float4*>(cb + (size_t)i * DG);
    float s = 0.0f;
    #pragma unroll
    for (int j = 0; j < 16; ++j) {
        float4 v = c4[j];
        s = fmaf(v.x, v.x, s); s = fmaf(v.y, v.y, s);
        s = fmaf(v.z, v.z, s); s = fmaf(v.w, v.w, s);
    }
    wcn[i] = s;
}

__device__ __forceinline__ float dotc(const float* __restrict__ a,
                                      const float* __restrict__ b)
{
    const float4* a4 = reinterpret_cast<const float4*>(a);
    const float4* b4 = reinterpret_cast<const float4*>(b);
    float s = 0.0f;
    #pragma unroll 4
    for (int j = 0; j < 16; ++j) {
        float4 u = a4[j], v = b4[j];
        s = fmaf(u.x, v.x, s); s = fmaf(u.y, v.y, s);
        s = fmaf(u.z, v.z, s); s = fmaf(u.w, v.w, s);
    }
    return s;
}

__device__ __forceinline__ bf16x8 cvt8(const float* __restrict__ p)
{
    float4 u = *reinterpret_cast<const float4*>(p);
    float4 v = *reinterpret_cast<const float4*>(p + 4);
    bf16x8 r;
    r[0]=(__bf16)u.x; r[1]=(__bf16)u.y; r[2]=(__bf16)u.z; r[3]=(__bf16)u.w;
    r[4]=(__bf16)v.x; r[5]=(__bf16)v.y; r[6]=(__bf16)v.z; r[7]=(__bf16)v.w;
    return r;
}

__device__ __forceinline__ bf16x8 ldfrag(const __bf16* __restrict__ wbg,
                                         int ct, int shalf, int lane)
{
    return *reinterpret_cast<const bf16x8*>(
        wbg + ((size_t)(ct * 2 + shalf) * 64 + lane) * 8);
}

// ---------------- main: screen + rescue ------------------------------------
// Block = 256 threads (4 waves). Wave handles 32 tokens x 1 group.
// Grid = 128 tiles * 8 groups = 1024 blocks (4/CU -> 16 waves/CU).
__global__ __launch_bounds__(256, 4) void vq_mfma_kernel(
    const float*  __restrict__ x,
    const float*  __restrict__ cb,
    const __bf16* __restrict__ wb,
    const float*  __restrict__ wcn,
    float* __restrict__ out)
{
    __shared__ float cn64[NCODE];

    const int tid  = threadIdx.x;
    const int lane = tid & 63;
    const int w    = tid >> 6;
    const int g    = blockIdx.x & 7;
    const int tile = blockIdx.x >> 3;

    {   // stage cn+64 for the screen (rescue uses true wcn from L2)
        float4 v = reinterpret_cast<const float4*>(wcn + g * NCODE)[tid];
        v.x += 64.0f; v.y += 64.0f; v.z += 64.0f; v.w += 64.0f;
        reinterpret_cast<float4*>(cn64)[tid] = v;
    }
    __syncthreads();

    const int row  = lane & 15;
    const int q    = lane >> 4;
    const int k0   = q * 8;
    const int tok0 = tile * 128 + w * 32;

    // per-wave phase offset (wave-uniform scalar) to break the load convoy
    const int off = __builtin_amdgcn_readfirstlane(((tile + w) & 3) * 16);

    // A fragments for 2 token-subtiles: row=lane&15, k = q*8+j (+32 for aB)
    bf16x8 aA[2], aB[2];
    #pragma unroll
    for (int s = 0; s < 2; ++s) {
        const float* xr = x + (size_t)(tok0 + s * 16 + row) * DMODEL + g * DG;
        aA[s] = cvt8(xr + k0);
        aB[s] = cvt8(xr + 32 + k0);
    }

    unsigned best[2][4], sec[2][4];
    #pragma unroll
    for (int s = 0; s < 2; ++s)
        #pragma unroll
        for (int r = 0; r < 4; ++r) { best[s][r] = 0xFFFFFFFFu; sec[s][r] = 0xFFFFFFFFu; }

    const __bf16* wbg = wb + (size_t)g * (NCODE * DG);
    const f32x4 zz = {0.0f, 0.0f, 0.0f, 0.0f};   // persistent C-operand

    // two named b-register sets -> prefetch distance 2
    bf16x8 b0a = ldfrag(wbg, off,            0, lane), b1a = ldfrag(wbg, off,            1, lane);
    bf16x8 b0b = ldfrag(wbg, (off + 1) & 63, 0, lane), b1b = ldfrag(wbg, (off + 1) & 63, 1, lane);

    for (int i = 0; i < 64; i += 2) {
        const int cta = (i + off) & 63;          // wave-uniform
        const int ctb = (i + 1 + off) & 63;
        const int pfa = (i + 2 + off) & 63;
        const int pfb = (i + 3 + off) & 63;
        // ---- tile cta (a-set) ----
        {
            f32x4 d[2];
            #pragma unroll
            for (int s = 0; s < 2; ++s) {
                f32x4 z = __builtin_amdgcn_mfma_f32_16x16x32_bf16(aA[s], b0a, zz, 0, 0, 0);
                d[s] = __builtin_amdgcn_mfma_f32_16x16x32_bf16(aB[s], b1a, z, 0, 0, 0);
            }
            b0a = ldfrag(wbg, pfa, 0, lane);     // wrap reload: harmless dup
            b1a = ldfrag(wbg, pfa, 1, lane);
            const int code = cta * 16 + row;
            const float cnv = cn64[code];
            #pragma unroll
            for (int s = 0; s < 2; ++s)
                #pragma unroll
                for (int r = 0; r < 4; ++r) {
                    float sd = fmaf(-2.0f, d[s][r], cnv);   // positive by construction
                    unsigned key = (__float_as_uint(sd) & 0xFFFFFC00u) | (unsigned)code;
                    unsigned bo  = best[s][r];
                    best[s][r] = umin_(bo, key);
                    sec[s][r]  = umin_(sec[s][r], umax_(bo, key));
                }
        }
        // ---- tile ctb (b-set) ----
        {
            f32x4 d[2];
            #pragma unroll
            for (int s = 0; s < 2; ++s) {
                f32x4 z = __builtin_amdgcn_mfma_f32_16x16x32_bf16(aA[s], b0b, zz, 0, 0, 0);
                d[s] = __builtin_amdgcn_mfma_f32_16x16x32_bf16(aB[s], b1b, z, 0, 0, 0);
            }
            b0b = ldfrag(wbg, pfb, 0, lane);
            b1b = ldfrag(wbg, pfb, 1, lane);
            const int code = ctb * 16 + row;
            const float cnv = cn64[code];
            #pragma unroll
            for (int s = 0; s < 2; ++s)
                #pragma unroll
                for (int r = 0; r < 4; ++r) {
                    float sd = fmaf(-2.0f, d[s][r], cnv);
                    unsigned key = (__float_as_uint(sd) & 0xFFFFFC00u) | (unsigned)code;
                    unsigned bo  = best[s][r];
                    best[s][r] = umin_(bo, key);
                    sec[s][r]  = umin_(sec[s][r], umax_(bo, key));
                }
        }
    }

    // min-reduce packed keys across each 16-lane col group (q-group)
    unsigned mk[2][4];
    #pragma unroll
    for (int s = 0; s < 2; ++s)
        #pragma unroll
        for (int r = 0; r < 4; ++r) mk[s][r] = best[s][r];
    #pragma unroll
    for (int mask = 1; mask < 16; mask <<= 1) {
        #pragma unroll
        for (int s = 0; s < 2; ++s)
            #pragma unroll
            for (int r = 0; r < 4; ++r) {
                unsigned o = (unsigned)__shfl_xor((int)mk[s][r], mask, 64);
                mk[s][r] = umin_(mk[s][r], o);
            }
    }

    const float* cbg  = cb  + (size_t)g * NCODE * DG;
    const float* wcng = wcn + (size_t)g * NCODE;

    #pragma unroll
    for (int s = 0; s < 2; ++s) {
        #pragma unroll
        for (int r = 0; r < 4; ++r) {
            const unsigned m_ = mk[s][r];
            int sel = (int)(m_ & 0x3FFu);
            const float thr = __uint_as_float(m_ & 0xFFFFFC00u) + EPS;
            const float bd  = __uint_as_float(best[s][r] & 0xFFFFFC00u);
            const float sdd = __uint_as_float(sec[s][r]  & 0xFFFFFC00u);
            const bool oth = (bd <= thr && best[s][r] != m_) || (sdd <= thr);
            const unsigned long long bal = __ballot(oth);
            if (((bal >> (q * 16)) & 0xFFFFULL) != 0ULL) {
                // exact fp32 rescue among tracked candidates
                const int token = tok0 + s * 16 + q * 4 + r;
                const float* xr = x + (size_t)token * DMODEL + g * DG;
                const float xn = dotc(xr, xr);
                float ed = 1e30f; int ei = 0x7FFFFFFF;
                if (bd <= thr) {
                    const int c = (int)(best[s][r] & 0x3FFu);
                    float dd = (xn + wcng[c]) - 2.0f * dotc(xr, cbg + (size_t)c * DG);
                    if (dd < ed || (dd == ed && c < ei)) { ed = dd; ei = c; }
                }
                if (sdd <= thr) {
                    const int c = (int)(sec[s][r] & 0x3FFu);
                    float dd = (xn + wcng[c]) - 2.0f * dotc(xr, cbg + (size_t)c * DG);
                    if (dd < ed || (dd == ed && c < ei)) { ed = dd; ei = c; }
                }
                #pragma unroll
                for (int mask = 1; mask < 16; mask <<= 1) {
                    float pd = __shfl_xor(ed, mask, 64);
                    int   pi = __shfl_xor(ei, mask, 64);
                    if (pd < ed || (pd == ed && pi < ei)) { ed = pd; ei = pi; }
                }
                sel = ei;
            }
            // write the selected code row (16 lanes x float4 = 64 floats)
            const int token = tok0 + s * 16 + q * 4 + r;
            const float4 src = reinterpret_cast<const float4*>(cbg + (size_t)sel * DG)[row];
            reinterpret_cast<float4*>(out + (size_t)token * DMODEL + g * DG)[row] = src;
        }
    }
}

// ---------------- fp32 fallback (ws too small) -----------------------------
__global__ __launch_bounds__(512, 4) void vq_fp32_kernel(
    const float* __restrict__ x,
    const float* __restrict__ cb,
    float* __restrict__ out)
{
    __shared__ float cnl[NGRP][NCODE];
    const int tid  = threadIdx.x;
    const int lane = tid & 63;
    const int wave = tid >> 6;
    const int g    = __builtin_amdgcn_readfirstlane(wave);
    const int token = blockIdx.x * 64 + lane;
    const float* __restrict__ cbg = cb + (size_t)g * NCODE * DG;

    for (int kk = lane; kk < NCODE; kk += 64) {
        const float4* c4 = reinterpret_cast<const float4*>(cbg + kk * DG);
        float s = 0.0f;
        #pragma unroll
        for (int j = 0; j < 16; ++j) {
            float4 v = c4[j];
            s = fmaf(v.x, v.x, s); s = fmaf(v.y, v.y, s);
            s = fmaf(v.z, v.z, s); s = fmaf(v.w, v.w, s);
        }
        cnl[g][kk] = s;
    }
    __syncthreads();

    const float* xr = x + (size_t)token * DMODEL + g * DG;
    float xn = dotc(xr, xr);
    float bestv = 3.4e38f; int bidx = 0;
    for (int k = 0; k < NCODE; ++k) {
        float dist = (xn + cnl[g][k]) - 2.0f * dotc(xr, cbg + (size_t)k * DG);
        if (dist < bestv) { bestv = dist; bidx = k; }
    }
    const float4* q4 = reinterpret_cast<const float4*>(cbg + (size_t)bidx * DG);
    float4* o4 = reinterpret_cast<float4*>(out + (size_t)token * DMODEL + g * DG);
    #pragma unroll
    for (int j = 0; j < 16; ++j) o4[j] = q4[j];
}

extern "C" void kernel_launch(void* const* d_in, const int* in_sizes, int n_in,
                              void* d_out, int out_size, void* d_ws, size_t ws_size,
                              hipStream_t stream) {
    const float* x  = (const float*)d_in[0];
    const float* cb = (const float*)d_in[1];
    float* out = (float*)d_out;

    const size_t wb_bytes = (size_t)NGRP * NCODE * DG * sizeof(__bf16); // 1 MB
    const size_t cn_bytes = (size_t)NGRP * NCODE * sizeof(float);       // 32 KB
    if (ws_size < wb_bytes + cn_bytes) {
        vq_fp32_kernel<<<256, 512, 0, stream>>>(x, cb, out);
        return;
    }
    __bf16* wb  = (__bf16*)d_ws;
    float*  wcn = (float*)((char*)d_ws + wb_bytes);

    prep_frags<<<256, 256, 0, stream>>>(cb, wb);
    prep_cnorm<<<32, 256, 0, stream>>>(cb, wcn);
    vq_mfma_kernel<<<1024, 256, 0, stream>>>(x, cb, wb, wcn, out);
}